// Round 5
// baseline (203.871 us; speedup 1.0000x reference)
//
#include <hip/hip_runtime.h>
#include <hip/hip_bf16.h>
#include <stdint.h>

// Problem constants
#define TOKS   262144      // B*S = 32*8192
#define NGRP   16384       // B*G = 32*512
#define EMB    1024
#define HD     64

using bf16x8 = __attribute__((ext_vector_type(8))) short;   // 8 bf16 (4 VGPRs) MFMA operand
using f32x4  = __attribute__((ext_vector_type(4))) float;   // MFMA accumulator

__device__ __forceinline__ unsigned pack2(float a, float b) {
    union { __hip_bfloat162 h; unsigned u; } cvt;
    cvt.h = __float22bfloat162_rn(make_float2(a, b));   // RNE pk-convert
    return cvt.u;
}
__device__ __forceinline__ bf16x8 cvt8(float4 v0, float4 v1) {
    uint4 u;
    u.x = pack2(v0.x, v0.y);
    u.y = pack2(v0.z, v0.w);
    u.z = pack2(v1.x, v1.y);
    u.w = pack2(v1.z, v1.w);
    return __builtin_bit_cast(bf16x8, u);
}
__device__ __forceinline__ void gload_lds16(const unsigned short* g, unsigned short* l) {
    __builtin_amdgcn_global_load_lds(
        (const __attribute__((address_space(1))) void*)g,
        (__attribute__((address_space(3))) void*)l,
        16, 0, 0);
}

// ---------------------------------------------------------------------------
// K0a: convert Wo (fp32 [1024][1024]) -> bf16
// ---------------------------------------------------------------------------
__global__ __launch_bounds__(256) void k_cvt_wo(const float* __restrict__ wo,
                                                unsigned short* __restrict__ out) {
    int idx = (blockIdx.x * 256 + threadIdx.x) * 4;
    float4 v = *(const float4*)(wo + idx);
    uint2 p;
    p.x = pack2(v.x, v.y);
    p.y = pack2(v.z, v.w);
    *(uint2*)(out + idx) = p;
}

// K0b: convert Wq|Wk|Wv (each fp32 [64][64]) -> bf16, packed [3][4096]
__global__ __launch_bounds__(256) void k_cvt_w3(const float* __restrict__ wq,
                                                const float* __restrict__ wk,
                                                const float* __restrict__ wv,
                                                unsigned short* __restrict__ dst) {
    int b = blockIdx.x;                 // 0..11
    int m = b >> 2;
    const float* src = (m == 0) ? wq : ((m == 1) ? wk : wv);
    int idx = ((b & 3) * 256 + threadIdx.x) * 4;
    float4 v = *(const float4*)(src + idx);
    uint2 p;
    p.x = pack2(v.x, v.y);
    p.y = pack2(v.z, v.w);
    *(uint2*)(dst + m * 4096 + idx) = p;
}

// ---------------------------------------------------------------------------
// K1: FUSED QKV projection + 16x16 attention, MFMA throughout.
// Block = 256 threads (4 waves). Each wave owns 64 tokens = 4 groups,
// one group per pass (LDS 18.4 KB/block -> 8 blocks/CU). Per-wave-private
// LDS, no barriers. W is pre-converted bf16 read straight into B-frags.
// Epilogue bounces O through LDS to emit 2 coalesced dwordx4 stores/group.
// ---------------------------------------------------------------------------
#define SCL 0.0450842200278f   /* log2(e)/32 */

__global__ __launch_bounds__(256) void k_fused(const float* __restrict__ x,
                                               const unsigned short* __restrict__ wqkv,
                                               unsigned short* __restrict__ out2) {
    // [wave][Q/K][16 x 72 bf16]  (pad 64->72 breaks bank aliasing)
    __shared__ __align__(16) unsigned short qkls[4][2][16 * 72];
    int t = threadIdx.x;
    int w = t >> 6, l = t & 63;
    int c = l & 15, q = l >> 4;
    int waveTok0 = blockIdx.x * 256 + w * 64;
    unsigned short* Qt = qkls[w][0];
    unsigned short* Kt = qkls[w][1];

    for (int g = 0; g < 4; ++g) {
        int gi = (waveTok0 >> 4) + g;

        // ---- x A-frags (fp32 -> bf16 in-register) ----
        const float* xp = x + (size_t)(waveTok0 + g * 16 + c) * 64 + q * 8;
        bf16x8 xa[2];
        #pragma unroll
        for (int kc = 0; kc < 2; ++kc) {
            float4 v0 = *(const float4*)(xp + kc * 32);
            float4 v1 = *(const float4*)(xp + kc * 32 + 4);
            xa[kc] = cvt8(v0, v1);
        }

        // ---- projections: Q,K -> LDS tiles; V stays in regs ----
        uint2 pkV[4];
        #pragma unroll
        for (int m = 0; m < 3; ++m) {
            #pragma unroll
            for (int nb = 0; nb < 4; ++nb) {
                const unsigned short* wp = wqkv + m * 4096 + (nb * 16 + c) * 64 + q * 8;
                bf16x8 w0 = *(const bf16x8*)(wp);
                bf16x8 w1 = *(const bf16x8*)(wp + 32);
                f32x4 acc = (f32x4){0.f, 0.f, 0.f, 0.f};
                acc = __builtin_amdgcn_mfma_f32_16x16x32_bf16(xa[0], w0, acc, 0, 0, 0);
                acc = __builtin_amdgcn_mfma_f32_16x16x32_bf16(xa[1], w1, acc, 0, 0, 0);
                unsigned u01 = pack2(acc[0], acc[1]);
                unsigned u23 = pack2(acc[2], acc[3]);
                if (m < 2) {
                    unsigned short* tile = qkls[w][m];
                    int base = 4 * q * 72 + nb * 16 + c;
                    tile[base]       = (unsigned short)u01;
                    tile[base + 72]  = (unsigned short)(u01 >> 16);
                    tile[base + 144] = (unsigned short)u23;
                    tile[base + 216] = (unsigned short)(u23 >> 16);
                } else {
                    pkV[nb].x = u01;    // tokens 4q+0,1
                    pkV[nb].y = u23;    // tokens 4q+2,3
                }
            }
        }

        // ---- energy^T[j][i]: A = K-frag, B = Q-frag ----
        f32x4 e = (f32x4){0.f, 0.f, 0.f, 0.f};
        #pragma unroll
        for (int kc = 0; kc < 2; ++kc) {
            bf16x8 ka = *(const bf16x8*)(Kt + c * 72 + kc * 32 + q * 8);
            bf16x8 qb = *(const bf16x8*)(Qt + c * 72 + kc * 32 + q * 8);
            e = __builtin_amdgcn_mfma_f32_16x16x32_bf16(ka, qb, e, 0, 0, 0);
        }
        // lane(q,c): e[r] = energy[i=c][j=4q+r]

        // ---- softmax over j ----
        float mx = fmaxf(fmaxf(e[0], e[1]), fmaxf(e[2], e[3]));
        mx = fmaxf(mx, __shfl_xor(mx, 16));
        mx = fmaxf(mx, __shfl_xor(mx, 32));
        float p0 = exp2f((e[0] - mx) * SCL);
        float p1 = exp2f((e[1] - mx) * SCL);
        float p2 = exp2f((e[2] - mx) * SCL);
        float p3 = exp2f((e[3] - mx) * SCL);
        float s = p0 + p1 + p2 + p3;
        s += __shfl_xor(s, 16);
        s += __shfl_xor(s, 32);
        float rinv = 1.0f / s;

        // ---- PV A-frag: attn[i=c][k=8q+jj], gathered from quads 2q,2q+1 ----
        unsigned pa0 = pack2(p0 * rinv, p1 * rinv);   // j = 4q+0,1
        unsigned pa1 = pack2(p2 * rinv, p3 * rinv);   // j = 4q+2,3
        int s0 = (32 * q + c) & 63;
        int s1 = (32 * q + 16 + c) & 63;
        int a0 = __shfl((int)pa0, s0);
        int a1 = __shfl((int)pa1, s0);
        int a2 = __shfl((int)pa0, s1);
        int a3 = __shfl((int)pa1, s1);
        uint4 A2u;
        bool hi = (q >= 2);                 // k >= 16 -> zero pad
        A2u.x = hi ? 0u : (unsigned)a0;
        A2u.y = hi ? 0u : (unsigned)a1;
        A2u.z = hi ? 0u : (unsigned)a2;
        A2u.w = hi ? 0u : (unsigned)a3;
        bf16x8 A2 = __builtin_bit_cast(bf16x8, A2u);

        // ---- PV: B-frag V[j=8q'+jj][d=16nb+c] via shuffles; O -> Qt (free) ----
        int v0 = 32 * (q & 1) + c;
        int v1 = v0 + 16;
        #pragma unroll
        for (int nb = 0; nb < 4; ++nb) {
            uint4 B2u;
            B2u.x = (unsigned)__shfl((int)pkV[nb].x, v0);
            B2u.y = (unsigned)__shfl((int)pkV[nb].y, v0);
            B2u.z = (unsigned)__shfl((int)pkV[nb].x, v1);
            B2u.w = (unsigned)__shfl((int)pkV[nb].y, v1);
            bf16x8 B2 = __builtin_bit_cast(bf16x8, B2u);
            f32x4 o = (f32x4){0.f, 0.f, 0.f, 0.f};
            o = __builtin_amdgcn_mfma_f32_16x16x32_bf16(A2, B2, o, 0, 0, 0);
            // o[r] = out[i=4q+r][d=16nb+c] -> stash in Qt tile
            unsigned u01 = pack2(o[0], o[1]);
            unsigned u23 = pack2(o[2], o[3]);
            int base = 4 * q * 72 + nb * 16 + c;
            Qt[base]       = (unsigned short)u01;
            Qt[base + 72]  = (unsigned short)(u01 >> 16);
            Qt[base + 144] = (unsigned short)u23;
            Qt[base + 216] = (unsigned short)(u23 >> 16);
        }

        // ---- coalesced store: lane l covers row l>>2, 16 cols ----
        int b    = gi >> 9;
        int grem = gi & 511;
        int rowbase = b * 512 + (grem >> 4);
        int colpref = (grem & 15) * 64;
        const unsigned short* osrc = Qt + (l >> 2) * 72 + (l & 3) * 16;
        uint4 ov0 = *(const uint4*)(osrc);
        uint4 ov1 = *(const uint4*)(osrc + 8);
        unsigned short* dst = out2 + (size_t)(rowbase + (l >> 2) * 32) * 1024
                                   + colpref + (l & 3) * 16;
        *(uint4*)(dst)     = ov0;
        *(uint4*)(dst + 8) = ov1;
    }
}

// ---------------------------------------------------------------------------
// K2: C[16384][1024] = out2 @ Wo^T + bo  (bf16 MFMA, fp32 acc/out)
// 128x128 tile, BK=64, 256 threads (4 waves, 2x2), 16x16x32 MFMA.
// global_load_lds width-16 staging with XOR chunk swizzle (j ^= row&7):
// staging keeps the wave-uniform-base + lane*16 constraint, reads become
// 2-way-at-worst on LDS banks. Band-major 1D grid for XCD L2 A-reuse.
// ---------------------------------------------------------------------------
__global__ __launch_bounds__(256) void k_gemm(const unsigned short* __restrict__ A,
                                              const unsigned short* __restrict__ Bm,
                                              const float* __restrict__ bias,
                                              float* __restrict__ C) {
    __shared__ __align__(16) unsigned short As[128 * 64];
    __shared__ __align__(16) unsigned short Bs[128 * 64];
    const int K = 1024;
    int t  = threadIdx.x;
    int id = blockIdx.x;
    int m0 = (id & 127) * 128;
    int n0 = (id >> 7) * 128;
    int w  = t >> 6;
    int l  = t & 63;
    int wm = (w & 1) * 64;
    int wn = (w >> 1) * 64;
    int lm = l & 15;
    int q4 = l >> 4;
    int jxor = lm & 7;

    // Staging: slot s = t + 256*qq holds row = s>>3, global chunk (s&7)^(row&7)
    const unsigned short* Ag[4];
    const unsigned short* Bg[4];
    #pragma unroll
    for (int qq = 0; qq < 4; ++qq) {
        int s   = t + 256 * qq;
        int row = s >> 3;
        int jg  = (s & 7) ^ (row & 7);
        Ag[qq] = A  + (size_t)(m0 + row) * K + jg * 8;
        Bg[qq] = Bm + (size_t)(n0 + row) * K + jg * 8;
    }

    f32x4 acc[4][4];
    #pragma unroll
    for (int mi = 0; mi < 4; ++mi)
        #pragma unroll
        for (int ni = 0; ni < 4; ++ni)
            acc[mi][ni] = (f32x4){0.f, 0.f, 0.f, 0.f};

    for (int k0 = 0; k0 < K; k0 += 64) {
        #pragma unroll
        for (int qq = 0; qq < 4; ++qq) {
            gload_lds16(Ag[qq] + k0, As + (size_t)(t + 256 * qq) * 8);
            gload_lds16(Bg[qq] + k0, Bs + (size_t)(t + 256 * qq) * 8);
        }
        __syncthreads();

        #pragma unroll
        for (int kc = 0; kc < 2; ++kc) {
            int joff = ((kc * 4 + q4) ^ jxor) * 8;
            bf16x8 af[4], bfr[4];
            #pragma unroll
            for (int mi = 0; mi < 4; ++mi)
                af[mi] = *(const bf16x8*)(As + (wm + mi * 16 + lm) * 64 + joff);
            #pragma unroll
            for (int ni = 0; ni < 4; ++ni)
                bfr[ni] = *(const bf16x8*)(Bs + (wn + ni * 16 + lm) * 64 + joff);
            #pragma unroll
            for (int mi = 0; mi < 4; ++mi)
                #pragma unroll
                for (int ni = 0; ni < 4; ++ni)
                    acc[mi][ni] = __builtin_amdgcn_mfma_f32_16x16x32_bf16(
                        af[mi], bfr[ni], acc[mi][ni], 0, 0, 0);
        }
        __syncthreads();
    }

    #pragma unroll
    for (int mi = 0; mi < 4; ++mi) {
        #pragma unroll
        for (int ni = 0; ni < 4; ++ni) {
            int col = n0 + wn + ni * 16 + lm;
            float bcol = bias[col];
            #pragma unroll
            for (int r = 0; r < 4; ++r) {
                int row = m0 + wm + mi * 16 + q4 * 4 + r;
                C[(size_t)row * 1024 + col] = acc[mi][ni][r] + bcol;
            }
        }
    }
}

// ---------------------------------------------------------------------------
extern "C" void kernel_launch(void* const* d_in, const int* in_sizes, int n_in,
                              void* d_out, int out_size, void* d_ws, size_t ws_size,
                              hipStream_t stream) {
    const float* x  = (const float*)d_in[0];
    const float* wq = (const float*)d_in[1];
    const float* wk = (const float*)d_in[2];
    const float* wv = (const float*)d_in[3];
    const float* wo = (const float*)d_in[4];
    const float* bo = (const float*)d_in[5];
    float* out = (float*)d_out;

    unsigned short* out2  = (unsigned short*)d_ws;           // 16384*1024 bf16 (32 MB)
    unsigned short* wob   = out2 + (size_t)NGRP * 1024;      // 1024*1024 bf16 (2 MB)
    unsigned short* wqkvb = wob + (size_t)EMB * EMB;         // 3*4096 bf16 (24 KB)

    k_cvt_wo<<<1024, 256, 0, stream>>>(wo, wob);
    k_cvt_w3<<<12,   256, 0, stream>>>(wq, wk, wv, wqkvb);
    k_fused<<<1024, 256, 0, stream>>>(x, wqkvb, out2);
    k_gemm <<<1024, 256, 0, stream>>>(out2, wob, bo, out);
}

// Round 6
// 178.114 us; speedup vs baseline: 1.1446x; 1.1446x over previous
//
#include <hip/hip_runtime.h>
#include <hip/hip_bf16.h>
#include <stdint.h>

// Problem constants
#define TOKS   262144      // B*S = 32*8192
#define NGRP   16384       // B*G = 32*512
#define EMB    1024
#define HD     64

using bf16x8 = __attribute__((ext_vector_type(8))) short;   // 8 bf16 (4 VGPRs) MFMA operand
using f32x4  = __attribute__((ext_vector_type(4))) float;   // MFMA accumulator

__device__ __forceinline__ unsigned pack2(float a, float b) {
    union { __hip_bfloat162 h; unsigned u; } cvt;
    cvt.h = __float22bfloat162_rn(make_float2(a, b));   // RNE pk-convert
    return cvt.u;
}
__device__ __forceinline__ bf16x8 cvt8(float4 v0, float4 v1) {
    uint4 u;
    u.x = pack2(v0.x, v0.y);
    u.y = pack2(v0.z, v0.w);
    u.z = pack2(v1.x, v1.y);
    u.w = pack2(v1.z, v1.w);
    return __builtin_bit_cast(bf16x8, u);
}
__device__ __forceinline__ void gload_lds16(const unsigned short* g, unsigned short* l) {
    __builtin_amdgcn_global_load_lds(
        (const __attribute__((address_space(1))) void*)g,
        (__attribute__((address_space(3))) void*)l,
        16, 0, 0);
}

// ---------------------------------------------------------------------------
// K0: convert Wo (fp32 [1024][1024]) -> bf16  (blocks 0..1023)
//     and Wq|Wk|Wv (fp32 [64][64] each) -> bf16 packed [3][4096] (blocks 1024..1035)
// ---------------------------------------------------------------------------
__global__ __launch_bounds__(256) void k_cvt(const float* __restrict__ wo,
                                             const float* __restrict__ wq,
                                             const float* __restrict__ wk,
                                             const float* __restrict__ wv,
                                             unsigned short* __restrict__ wob,
                                             unsigned short* __restrict__ wqkvb) {
    int bid = blockIdx.x;
    if (bid < 1024) {
        int idx = (bid * 256 + threadIdx.x) * 4;
        float4 v = *(const float4*)(wo + idx);
        uint2 p;
        p.x = pack2(v.x, v.y);
        p.y = pack2(v.z, v.w);
        *(uint2*)(wob + idx) = p;
    } else {
        int b = bid - 1024;                 // 0..11
        int m = b >> 2;
        const float* src = (m == 0) ? wq : ((m == 1) ? wk : wv);
        int idx = ((b & 3) * 256 + threadIdx.x) * 4;
        float4 v = *(const float4*)(src + idx);
        uint2 p;
        p.x = pack2(v.x, v.y);
        p.y = pack2(v.z, v.w);
        *(uint2*)(wqkvb + m * 4096 + idx) = p;
    }
}

// ---------------------------------------------------------------------------
// K1: FUSED QKV projection + 16x16 attention, MFMA throughout.
// Block = 256 threads (4 waves) = 128 tokens. Each wave owns 32 tokens =
// 2 groups, processed TOGETHER (interleaved) for ILP — the per-group chain
// (proj MFMAs -> LDS -> energy MFMA -> softmax shuffles -> PV bpermutes)
// is serial; two independent chains give the scheduler overlap. (R4's
// 1-group/pass variant regressed 56->74 us: grid-limited occupancy meant
// the lost ILP could not be bought back with waves.)
// Per-wave-private LDS (36.9 KB/block), no barriers. W pre-converted bf16.
// Epilogue bounces O through LDS -> 2 coalesced dwordx4 stores per group.
// ---------------------------------------------------------------------------
#define SCL 0.0450842200278f   /* log2(e)/32 */

__global__ __launch_bounds__(256) void k_fused(const float* __restrict__ x,
                                               const unsigned short* __restrict__ wqkv,
                                               unsigned short* __restrict__ out2) {
    // [wave][group][Q/K][16 x 72 bf16]  (pad 64->72 breaks bank aliasing)
    __shared__ __align__(16) unsigned short qkls[4][2][2][16 * 72];
    int t = threadIdx.x;
    int w = t >> 6, l = t & 63;
    int c = l & 15, q = l >> 4;
    int waveTok0 = blockIdx.x * 128 + w * 32;

    // ---- x A-frags for both groups (fp32 -> bf16 in-register) ----
    bf16x8 xa[2][2];
    #pragma unroll
    for (int g = 0; g < 2; ++g) {
        const float* xp = x + (size_t)(waveTok0 + g * 16 + c) * 64 + q * 8;
        #pragma unroll
        for (int kc = 0; kc < 2; ++kc) {
            float4 v0 = *(const float4*)(xp + kc * 32);
            float4 v1 = *(const float4*)(xp + kc * 32 + 4);
            xa[g][kc] = cvt8(v0, v1);
        }
    }

    // ---- projections: Q,K -> LDS tiles; V stays in regs ----
    uint2 pkV[2][4];
    #pragma unroll
    for (int m = 0; m < 3; ++m) {
        #pragma unroll
        for (int nb = 0; nb < 4; ++nb) {
            const unsigned short* wp = wqkv + m * 4096 + (nb * 16 + c) * 64 + q * 8;
            bf16x8 w0 = *(const bf16x8*)(wp);
            bf16x8 w1 = *(const bf16x8*)(wp + 32);
            #pragma unroll
            for (int g = 0; g < 2; ++g) {
                f32x4 acc = (f32x4){0.f, 0.f, 0.f, 0.f};
                acc = __builtin_amdgcn_mfma_f32_16x16x32_bf16(xa[g][0], w0, acc, 0, 0, 0);
                acc = __builtin_amdgcn_mfma_f32_16x16x32_bf16(xa[g][1], w1, acc, 0, 0, 0);
                unsigned u01 = pack2(acc[0], acc[1]);
                unsigned u23 = pack2(acc[2], acc[3]);
                if (m < 2) {
                    unsigned short* tile = qkls[w][g][m];
                    int base = 4 * q * 72 + nb * 16 + c;
                    tile[base]       = (unsigned short)u01;
                    tile[base + 72]  = (unsigned short)(u01 >> 16);
                    tile[base + 144] = (unsigned short)u23;
                    tile[base + 216] = (unsigned short)(u23 >> 16);
                } else {
                    pkV[g][nb].x = u01;    // tokens 4q+0,1
                    pkV[g][nb].y = u23;    // tokens 4q+2,3
                }
            }
        }
    }

    // ---- energy^T[j][i] for both groups: A = K-frag, B = Q-frag ----
    f32x4 e[2];
    #pragma unroll
    for (int g = 0; g < 2; ++g) {
        const unsigned short* Qt = qkls[w][g][0];
        const unsigned short* Kt = qkls[w][g][1];
        e[g] = (f32x4){0.f, 0.f, 0.f, 0.f};
        #pragma unroll
        for (int kc = 0; kc < 2; ++kc) {
            bf16x8 ka = *(const bf16x8*)(Kt + c * 72 + kc * 32 + q * 8);
            bf16x8 qb = *(const bf16x8*)(Qt + c * 72 + kc * 32 + q * 8);
            e[g] = __builtin_amdgcn_mfma_f32_16x16x32_bf16(ka, qb, e[g], 0, 0, 0);
        }
    }
    // lane(q,c): e[g][r] = energy[i=c][j=4q+r]

    // ---- softmax over j (both groups interleaved) ----
    unsigned pa0[2], pa1[2];
    #pragma unroll
    for (int g = 0; g < 2; ++g) {
        float mx = fmaxf(fmaxf(e[g][0], e[g][1]), fmaxf(e[g][2], e[g][3]));
        mx = fmaxf(mx, __shfl_xor(mx, 16));
        mx = fmaxf(mx, __shfl_xor(mx, 32));
        float p0 = exp2f((e[g][0] - mx) * SCL);
        float p1 = exp2f((e[g][1] - mx) * SCL);
        float p2 = exp2f((e[g][2] - mx) * SCL);
        float p3 = exp2f((e[g][3] - mx) * SCL);
        float s = p0 + p1 + p2 + p3;
        s += __shfl_xor(s, 16);
        s += __shfl_xor(s, 32);
        float rinv = 1.0f / s;
        pa0[g] = pack2(p0 * rinv, p1 * rinv);   // j = 4q+0,1
        pa1[g] = pack2(p2 * rinv, p3 * rinv);   // j = 4q+2,3
    }

    // ---- PV for both groups ----
    int s0 = (32 * q + c) & 63;
    int s1 = (32 * q + 16 + c) & 63;
    int v0 = 32 * (q & 1) + c;
    int v1 = v0 + 16;
    bool hi = (q >= 2);                 // k >= 16 -> zero pad
    #pragma unroll
    for (int g = 0; g < 2; ++g) {
        // A-frag: attn[i=c][k=8q+jj], gathered from quads 2q,2q+1
        int a0 = __shfl((int)pa0[g], s0);
        int a1 = __shfl((int)pa1[g], s0);
        int a2 = __shfl((int)pa0[g], s1);
        int a3 = __shfl((int)pa1[g], s1);
        uint4 A2u;
        A2u.x = hi ? 0u : (unsigned)a0;
        A2u.y = hi ? 0u : (unsigned)a1;
        A2u.z = hi ? 0u : (unsigned)a2;
        A2u.w = hi ? 0u : (unsigned)a3;
        bf16x8 A2 = __builtin_bit_cast(bf16x8, A2u);

        // B-frag V[j=8q'+jj][d=16nb+c] via shuffles; O -> Q tile (done being read)
        unsigned short* Ot = qkls[w][g][0];
        #pragma unroll
        for (int nb = 0; nb < 4; ++nb) {
            uint4 B2u;
            B2u.x = (unsigned)__shfl((int)pkV[g][nb].x, v0);
            B2u.y = (unsigned)__shfl((int)pkV[g][nb].y, v0);
            B2u.z = (unsigned)__shfl((int)pkV[g][nb].x, v1);
            B2u.w = (unsigned)__shfl((int)pkV[g][nb].y, v1);
            bf16x8 B2 = __builtin_bit_cast(bf16x8, B2u);
            f32x4 o = (f32x4){0.f, 0.f, 0.f, 0.f};
            o = __builtin_amdgcn_mfma_f32_16x16x32_bf16(A2, B2, o, 0, 0, 0);
            // o[r] = out[i=4q+r][d=16nb+c] -> stash
            unsigned u01 = pack2(o[0], o[1]);
            unsigned u23 = pack2(o[2], o[3]);
            int base = 4 * q * 72 + nb * 16 + c;
            Ot[base]       = (unsigned short)u01;
            Ot[base + 72]  = (unsigned short)(u01 >> 16);
            Ot[base + 144] = (unsigned short)u23;
            Ot[base + 216] = (unsigned short)(u23 >> 16);
        }
    }

    // ---- coalesced stores: lane l covers row l>>2, 16 cols, per group ----
    #pragma unroll
    for (int g = 0; g < 2; ++g) {
        int gi = (waveTok0 >> 4) + g;
        int b    = gi >> 9;
        int grem = gi & 511;
        int rowbase = b * 512 + (grem >> 4);
        int colpref = (grem & 15) * 64;
        const unsigned short* osrc = qkls[w][g][0] + (l >> 2) * 72 + (l & 3) * 16;
        uint4 ov0 = *(const uint4*)(osrc);
        uint4 ov1 = *(const uint4*)(osrc + 8);
        unsigned short* dst = out2 + (size_t)(rowbase + (l >> 2) * 32) * 1024
                                   + colpref + (l & 3) * 16;
        *(uint4*)(dst)     = ov0;
        *(uint4*)(dst + 8) = ov1;
    }
}

// ---------------------------------------------------------------------------
// K2: C[16384][1024] = out2 @ Wo^T + bo  (bf16 MFMA, fp32 acc/out)
// 128x128 tile, BK=64, 256 threads (4 waves, 2x2), 16x16x32 MFMA.
// global_load_lds width-16 staging with XOR chunk swizzle (j ^= row&7):
// staging keeps the wave-uniform-base + lane*16 constraint, reads become
// 2-way-at-worst on LDS banks. Band-major 1D grid for XCD L2 A-reuse.
// ---------------------------------------------------------------------------
__global__ __launch_bounds__(256) void k_gemm(const unsigned short* __restrict__ A,
                                              const unsigned short* __restrict__ Bm,
                                              const float* __restrict__ bias,
                                              float* __restrict__ C) {
    __shared__ __align__(16) unsigned short As[128 * 64];
    __shared__ __align__(16) unsigned short Bs[128 * 64];
    const int K = 1024;
    int t  = threadIdx.x;
    int id = blockIdx.x;
    int m0 = (id & 127) * 128;
    int n0 = (id >> 7) * 128;
    int w  = t >> 6;
    int l  = t & 63;
    int wm = (w & 1) * 64;
    int wn = (w >> 1) * 64;
    int lm = l & 15;
    int q4 = l >> 4;
    int jxor = lm & 7;

    // Staging: slot s = t + 256*qq holds row = s>>3, global chunk (s&7)^(row&7)
    const unsigned short* Ag[4];
    const unsigned short* Bg[4];
    #pragma unroll
    for (int qq = 0; qq < 4; ++qq) {
        int s   = t + 256 * qq;
        int row = s >> 3;
        int jg  = (s & 7) ^ (row & 7);
        Ag[qq] = A  + (size_t)(m0 + row) * K + jg * 8;
        Bg[qq] = Bm + (size_t)(n0 + row) * K + jg * 8;
    }

    f32x4 acc[4][4];
    #pragma unroll
    for (int mi = 0; mi < 4; ++mi)
        #pragma unroll
        for (int ni = 0; ni < 4; ++ni)
            acc[mi][ni] = (f32x4){0.f, 0.f, 0.f, 0.f};

    for (int k0 = 0; k0 < K; k0 += 64) {
        #pragma unroll
        for (int qq = 0; qq < 4; ++qq) {
            gload_lds16(Ag[qq] + k0, As + (size_t)(t + 256 * qq) * 8);
            gload_lds16(Bg[qq] + k0, Bs + (size_t)(t + 256 * qq) * 8);
        }
        __syncthreads();

        #pragma unroll
        for (int kc = 0; kc < 2; ++kc) {
            int joff = ((kc * 4 + q4) ^ jxor) * 8;
            bf16x8 af[4], bfr[4];
            #pragma unroll
            for (int mi = 0; mi < 4; ++mi)
                af[mi] = *(const bf16x8*)(As + (wm + mi * 16 + lm) * 64 + joff);
            #pragma unroll
            for (int ni = 0; ni < 4; ++ni)
                bfr[ni] = *(const bf16x8*)(Bs + (wn + ni * 16 + lm) * 64 + joff);
            #pragma unroll
            for (int mi = 0; mi < 4; ++mi)
                #pragma unroll
                for (int ni = 0; ni < 4; ++ni)
                    acc[mi][ni] = __builtin_amdgcn_mfma_f32_16x16x32_bf16(
                        af[mi], bfr[ni], acc[mi][ni], 0, 0, 0);
        }
        __syncthreads();
    }

    #pragma unroll
    for (int mi = 0; mi < 4; ++mi) {
        #pragma unroll
        for (int ni = 0; ni < 4; ++ni) {
            int col = n0 + wn + ni * 16 + lm;
            float bcol = bias[col];
            #pragma unroll
            for (int r = 0; r < 4; ++r) {
                int row = m0 + wm + mi * 16 + q4 * 4 + r;
                C[(size_t)row * 1024 + col] = acc[mi][ni][r] + bcol;
            }
        }
    }
}

// ---------------------------------------------------------------------------
extern "C" void kernel_launch(void* const* d_in, const int* in_sizes, int n_in,
                              void* d_out, int out_size, void* d_ws, size_t ws_size,
                              hipStream_t stream) {
    const float* x  = (const float*)d_in[0];
    const float* wq = (const float*)d_in[1];
    const float* wk = (const float*)d_in[2];
    const float* wv = (const float*)d_in[3];
    const float* wo = (const float*)d_in[4];
    const float* bo = (const float*)d_in[5];
    float* out = (float*)d_out;

    unsigned short* out2  = (unsigned short*)d_ws;           // 16384*1024 bf16 (32 MB)
    unsigned short* wob   = out2 + (size_t)NGRP * 1024;      // 1024*1024 bf16 (2 MB)
    unsigned short* wqkvb = wob + (size_t)EMB * EMB;         // 3*4096 bf16 (24 KB)

    k_cvt  <<<1036, 256, 0, stream>>>(wo, wq, wk, wv, wob, wqkvb);
    k_fused<<<2048, 256, 0, stream>>>(x, wqkvb, out2);
    k_gemm <<<1024, 256, 0, stream>>>(out2, wob, bo, out);
}